// Round 5
// baseline (308.756 us; speedup 1.0000x reference)
//
#include <hip/hip_runtime.h>
#include <math.h>

#define VOCAB 32000
#define BATCH 16
#define SEQ   512
#define RPL   8           // DP rows per lane in editdist
#define NED   16          // editdist blocks (one per batch)
#define NAMX  1024        // argmax blocks (4 waves each, 2 rows per wave)

typedef float floatx4 __attribute__((ext_vector_type(4)));

// ---------------------------------------------------------------------------
// init: zero the words flags (0 = not ready) and the output accumulator.
// ---------------------------------------------------------------------------
__global__ void init_kernel(int* __restrict__ words, float* __restrict__ out) {
    int g = blockIdx.x * 256 + threadIdx.x;
    if (g < BATCH * SEQ) words[g] = 0;
    if (g == 0) out[0] = 0.0f;
}

// ---------------------------------------------------------------------------
// Fused kernel.
//   blocks 0..15      : editdist consumer for batch b = blockIdx.x (wave 0 only)
//   blocks 16..16+1023: argmax producer; wave wgid handles rows in j-major
//                       order so words arrive in increasing-j bursts.
// Words are published as idx+1 via relaxed agent-scope atomics (payload-only
// dependency => no fence needed; agent scope => cross-XCD visible).
// ---------------------------------------------------------------------------
__global__ __launch_bounds__(256) void fused_kernel(const float* __restrict__ logits,
                                                    const int* __restrict__ target,
                                                    int* __restrict__ words,
                                                    float* __restrict__ out) {
    const int wid  = threadIdx.x >> 6;
    const int lane = threadIdx.x & 63;

    if (blockIdx.x < NED) {
        // ================= editdist consumer =================
        if (wid != 0) return;                  // wave 0 only
        const int b = blockIdx.x;
        const int t = lane;

        // lane t owns TARGET rows t*8+1 .. t*8+8 (symmetric edit distance)
        int myt[RPL];
        #pragma unroll
        for (int r = 0; r < RPL; ++r)
            myt[r] = target[b * SEQ + t * RPL + r] + 1;   // +1 to match stored idx+1

        int colv[RPL];
        #pragma unroll
        for (int r = 0; r < RPL; ++r) colv[r] = t * RPL + 1 + r;
        int prev_up = t * RPL;

        // lane 0 word pipeline: p0 = word[s-1] (use at step s), p1 = word[s]
        const int* wptr = words + b * SEQ;
        int p0 = 0, p1 = 0;
        if (t == 0) {
            p0 = __hip_atomic_load(&wptr[0], __ATOMIC_RELAXED, __HIP_MEMORY_SCOPE_AGENT);
            p1 = __hip_atomic_load(&wptr[1], __ATOMIC_RELAXED, __HIP_MEMORY_SCOPE_AGENT);
        }

        int w_prev = 0;   // word this lane used last step
        const int NSTEP = SEQ + 63;              // 575
        for (int s = 1; s <= NSTEP; ++s) {
            // ---- word stream: lane t gets lane t-1's previous word ----
            int w_this = __shfl_up(w_prev, 1, 64);
            if (t == 0) {
                if (s <= SEQ) {
                    while (p0 == 0) {            // spin until producer publishes
                        __builtin_amdgcn_s_sleep(2);
                        p0 = __hip_atomic_load(&wptr[s - 1], __ATOMIC_RELAXED,
                                               __HIP_MEMORY_SCOPE_AGENT);
                    }
                    w_this = p0;
                    p0 = p1;                     // rotate pipeline
                    p1 = (s + 1 <= SEQ)
                       ? __hip_atomic_load(&wptr[s + 1], __ATOMIC_RELAXED,
                                           __HIP_MEMORY_SCOPE_AGENT)
                       : 0;
                }
            }

            int up_in = __shfl_up(colv[RPL - 1], 1, 64);
            if (t == 0) up_in = s;               // E[0][j] = j

            const int j = s - t;
            if (j >= 1 && j <= SEQ) {
                // off-chain: mp[r] = min(left, diag - eq) + 1
                int mp[RPL];
                mp[0] = min(colv[0], prev_up - (myt[0] == w_this ? 1 : 0)) + 1;
                #pragma unroll
                for (int r = 1; r < RPL; ++r)
                    mp[r] = min(colv[r], colv[r - 1] - (myt[r] == w_this ? 1 : 0)) + 1;
                // serial chain: 2 dependent ops per row
                int u = up_in;
                #pragma unroll
                for (int r = 0; r < RPL; ++r) {
                    u = min(u + 1, mp[r]);
                    colv[r] = u;
                }
                prev_up = up_in;
            }
            w_prev = w_this;
        }

        if (t == 63)
            atomicAdd(out, (float)colv[RPL - 1] * (1.0f / ((float)BATCH * (float)SEQ)));
        return;
    }

    // ================= argmax producer =================
    const int wgid = (blockIdx.x - NED) * 4 + wid;        // 0..4095
    #pragma unroll
    for (int k = 0; k < 2; ++k) {
        const int l   = k * 4096 + wgid;                  // j-major row index
        const int row = (l & 15) * SEQ + (l >> 4);        // b*512 + j
        const floatx4* base4 = (const floatx4*)(logits + (size_t)row * VOCAB);

        float best = -INFINITY;
        int bestIdx = 0x7FFFFFFF;

        #pragma unroll 5
        for (int kk = lane; kk < VOCAB / 4; kk += 64) {
            floatx4 v = __builtin_nontemporal_load(base4 + kk);
            int i0 = kk * 4;
            if (v.x > best) { best = v.x; bestIdx = i0;     }
            if (v.y > best) { best = v.y; bestIdx = i0 + 1; }
            if (v.z > best) { best = v.z; bestIdx = i0 + 2; }
            if (v.w > best) { best = v.w; bestIdx = i0 + 3; }
        }

        for (int off = 32; off > 0; off >>= 1) {
            float ov = __shfl_down(best, off, 64);
            int   oi = __shfl_down(bestIdx, off, 64);
            if (ov > best || (ov == best && oi < bestIdx)) { best = ov; bestIdx = oi; }
        }
        if (lane == 0)
            __hip_atomic_store(&words[row], bestIdx + 1, __ATOMIC_RELAXED,
                               __HIP_MEMORY_SCOPE_AGENT);
    }
}

extern "C" void kernel_launch(void* const* d_in, const int* in_sizes, int n_in,
                              void* d_out, int out_size, void* d_ws, size_t ws_size,
                              hipStream_t stream) {
    const float* logits = (const float*)d_in[0];
    const int*   target = (const int*)d_in[1];

    int* words = (int*)d_ws;       // BATCH*SEQ ints (0 = not ready, else idx+1)
    float* out = (float*)d_out;

    init_kernel<<<(BATCH * SEQ + 255) / 256, 256, 0, stream>>>(words, out);
    fused_kernel<<<NED + NAMX, 256, 0, stream>>>(logits, target, words, out);
}

// Round 6
// 275.300 us; speedup vs baseline: 1.1215x; 1.1215x over previous
//
#include <hip/hip_runtime.h>
#include <math.h>

#define VOCAB 32000
#define BATCH 16
#define SEQ   512
#define RPL   8   // DP rows per lane in editdist

typedef float floatx4 __attribute__((ext_vector_type(4)));

// ---------------------------------------------------------------------------
// Kernel 1: argmax over vocab axis. One WAVE per (b,s) row; 4 waves/block.
// Each wave streams a contiguous 128 KB row with plain float4 loads
// (nontemporal removed this round — A/B vs R4). First-occurrence tie-break.
// Also zeroes out[0] for the fused finalize (safe: kernels serialize).
// ---------------------------------------------------------------------------
__global__ __launch_bounds__(256) void argmax_kernel(const float* __restrict__ logits,
                                                     int* __restrict__ words,
                                                     float* __restrict__ out) {
    if (blockIdx.x == 0 && threadIdx.x == 0) out[0] = 0.0f;

    const int wid  = threadIdx.x >> 6;          // wave in block: 0..3
    const int lane = threadIdx.x & 63;
    const int row  = blockIdx.x * 4 + wid;      // 0 .. BATCH*SEQ-1
    const floatx4* base4 = (const floatx4*)(logits + (size_t)row * VOCAB);

    float best = -INFINITY;
    int bestIdx = 0x7FFFFFFF;

    // 8000 float4 / 64 lanes = 125 iterations, contiguous 1 KB per wave-step.
    #pragma unroll 5
    for (int k = lane; k < VOCAB / 4; k += 64) {
        floatx4 v = base4[k];
        int i0 = k * 4;
        if (v.x > best) { best = v.x; bestIdx = i0;     }
        if (v.y > best) { best = v.y; bestIdx = i0 + 1; }
        if (v.z > best) { best = v.z; bestIdx = i0 + 2; }
        if (v.w > best) { best = v.w; bestIdx = i0 + 3; }
    }

    // 64-lane reduction, lower-index tie-break
    for (int off = 32; off > 0; off >>= 1) {
        float ov = __shfl_down(best, off, 64);
        int   oi = __shfl_down(bestIdx, off, 64);
        if (ov > best || (ov == best && oi < bestIdx)) { best = ov; bestIdx = oi; }
    }
    if (lane == 0) words[row] = bestIdx;
}

// ---------------------------------------------------------------------------
// Kernel 2: Levenshtein DP — single-wave staggered column march, no barriers.
// Lane t owns DP rows t*8+1..t*8+8 in registers; at step s it processes
// column j = s - t. Off-chain precompute mp[r] = min(left, diag-eq)+1 keeps
// the serial chain at 2 ops/row: u = min(u+1, mp[r]).
// Fused finalize: lane 63 atomicAdds dist/(B*S) into out[0] (exact dyadic
// rationals -> order-independent, deterministic).
// ---------------------------------------------------------------------------
__global__ __launch_bounds__(64) void editdist_kernel(const int* __restrict__ words,
                                                      const int* __restrict__ target,
                                                      float* __restrict__ out) {
    const int b = blockIdx.x;
    const int t = threadIdx.x;      // lane 0..63

    __shared__ int s_tg[SEQ];
    #pragma unroll
    for (int k = 0; k < RPL; ++k)
        s_tg[t + 64 * k] = target[b * SEQ + t + 64 * k];
    __syncthreads();

    int myw[RPL];
    #pragma unroll
    for (int r = 0; r < RPL; ++r)
        myw[r] = words[b * SEQ + t * RPL + r];

    // column 0: colv[r] = D[t*8+1+r][0] = t*8+1+r ; prev_up = D[t*8][0]
    int colv[RPL];
    #pragma unroll
    for (int r = 0; r < RPL; ++r) colv[r] = t * RPL + 1 + r;
    int prev_up = t * RPL;

    const int NSTEP = SEQ + 63;     // 575
    for (int s = 1; s <= NSTEP; ++s) {
        int up_in = __shfl_up(colv[RPL - 1], 1, 64);   // D[t*8][j] from lane t-1
        const int j = s - t;
        if (t == 0) up_in = s;                          // D[0][j] = j
        if (j >= 1 && j <= SEQ) {
            const int tgj = s_tg[j - 1];
            // off-chain: mp[r] = min(left, diag - eq) + 1
            int mp[RPL];
            mp[0] = min(colv[0], prev_up - (myw[0] == tgj ? 1 : 0)) + 1;
            #pragma unroll
            for (int r = 1; r < RPL; ++r)
                mp[r] = min(colv[r], colv[r - 1] - (myw[r] == tgj ? 1 : 0)) + 1;
            // serial chain: 2 dependent ops per row
            int u = up_in;
            #pragma unroll
            for (int r = 0; r < RPL; ++r) {
                u = min(u + 1, mp[r]);
                colv[r] = u;
            }
            prev_up = up_in;
        }
    }

    if (t == 63)
        atomicAdd(out, (float)colv[RPL - 1] * (1.0f / ((float)BATCH * (float)SEQ)));
}

extern "C" void kernel_launch(void* const* d_in, const int* in_sizes, int n_in,
                              void* d_out, int out_size, void* d_ws, size_t ws_size,
                              hipStream_t stream) {
    const float* logits = (const float*)d_in[0];
    const int*   target = (const int*)d_in[1];

    int* words = (int*)d_ws;   // BATCH*SEQ ints
    float* out = (float*)d_out;

    argmax_kernel<<<BATCH * SEQ / 4, 256, 0, stream>>>(logits, words, out);
    editdist_kernel<<<BATCH, 64, 0, stream>>>(words, target, out);
}

// Round 7
// 254.305 us; speedup vs baseline: 1.2141x; 1.0826x over previous
//
#include <hip/hip_runtime.h>
#include <math.h>

#define VOCAB 32000
#define BATCH 16
#define SEQ   512
#define RPL   8   // DP rows per lane in editdist
#define NBLK  125 // 1KB wave-blocks per row (8000 float4 / 64 lanes)

typedef float floatx4 __attribute__((ext_vector_type(4)));

// ---------------------------------------------------------------------------
// Kernel 1: argmax over vocab axis. One WAVE per (b,s) row; 4 waves/block.
// Nontemporal float4 loads (R6 A/B: nt = -22 µs). Per-row circular stagger:
// wave for row r starts at 1KB-block (r % 125) and wraps, decorrelating the
// channel-selecting low address bits across the 8192 concurrent streams.
// Explicit lower-index tie-break (visit order is no longer index order).
// ---------------------------------------------------------------------------
__global__ __launch_bounds__(256) void argmax_kernel(const float* __restrict__ logits,
                                                     int* __restrict__ words,
                                                     float* __restrict__ out) {
    if (blockIdx.x == 0 && threadIdx.x == 0) out[0] = 0.0f;

    const int wid  = threadIdx.x >> 6;          // wave in block: 0..3
    const int lane = threadIdx.x & 63;
    const int row  = blockIdx.x * 4 + wid;      // 0 .. BATCH*SEQ-1
    const floatx4* base4 = (const floatx4*)(logits + (size_t)row * VOCAB);

    const int shift = row % NBLK;               // starting 1KB block

    float best = -INFINITY;
    int bestIdx = 0x7FFFFFFF;

    #pragma unroll 5
    for (int it = 0; it < NBLK; ++it) {
        int blk = it + shift;
        if (blk >= NBLK) blk -= NBLK;           // circular wrap
        const int k = blk * 64 + lane;
        floatx4 v = __builtin_nontemporal_load(base4 + k);
        const int i0 = k * 4;
        if (v.x > best || (v.x == best && i0     < bestIdx)) { best = v.x; bestIdx = i0;     }
        if (v.y > best || (v.y == best && i0 + 1 < bestIdx)) { best = v.y; bestIdx = i0 + 1; }
        if (v.z > best || (v.z == best && i0 + 2 < bestIdx)) { best = v.z; bestIdx = i0 + 2; }
        if (v.w > best || (v.w == best && i0 + 3 < bestIdx)) { best = v.w; bestIdx = i0 + 3; }
    }

    // 64-lane reduction, lower-index tie-break
    for (int off = 32; off > 0; off >>= 1) {
        float ov = __shfl_down(best, off, 64);
        int   oi = __shfl_down(bestIdx, off, 64);
        if (ov > best || (ov == best && oi < bestIdx)) { best = ov; bestIdx = oi; }
    }
    if (lane == 0) words[row] = bestIdx;
}

// ---------------------------------------------------------------------------
// Kernel 2: Levenshtein DP — single-wave staggered column march, no barriers.
// Lane t owns DP rows t*8+1..t*8+8 in registers; at step s it processes
// column j = s - t. Off-chain precompute mp[r] = min(left, diag-eq)+1 keeps
// the serial chain at 2 ops/row. Fused finalize via exact-dyadic atomicAdd.
// ---------------------------------------------------------------------------
__global__ __launch_bounds__(64) void editdist_kernel(const int* __restrict__ words,
                                                      const int* __restrict__ target,
                                                      float* __restrict__ out) {
    const int b = blockIdx.x;
    const int t = threadIdx.x;      // lane 0..63

    __shared__ int s_tg[SEQ];
    #pragma unroll
    for (int k = 0; k < RPL; ++k)
        s_tg[t + 64 * k] = target[b * SEQ + t + 64 * k];
    __syncthreads();

    int myw[RPL];
    #pragma unroll
    for (int r = 0; r < RPL; ++r)
        myw[r] = words[b * SEQ + t * RPL + r];

    int colv[RPL];
    #pragma unroll
    for (int r = 0; r < RPL; ++r) colv[r] = t * RPL + 1 + r;
    int prev_up = t * RPL;

    const int NSTEP = SEQ + 63;     // 575
    for (int s = 1; s <= NSTEP; ++s) {
        int up_in = __shfl_up(colv[RPL - 1], 1, 64);   // D[t*8][j] from lane t-1
        const int j = s - t;
        if (t == 0) up_in = s;                          // D[0][j] = j
        if (j >= 1 && j <= SEQ) {
            const int tgj = s_tg[j - 1];
            int mp[RPL];
            mp[0] = min(colv[0], prev_up - (myw[0] == tgj ? 1 : 0)) + 1;
            #pragma unroll
            for (int r = 1; r < RPL; ++r)
                mp[r] = min(colv[r], colv[r - 1] - (myw[r] == tgj ? 1 : 0)) + 1;
            int u = up_in;
            #pragma unroll
            for (int r = 0; r < RPL; ++r) {
                u = min(u + 1, mp[r]);
                colv[r] = u;
            }
            prev_up = up_in;
        }
    }

    if (t == 63)
        atomicAdd(out, (float)colv[RPL - 1] * (1.0f / ((float)BATCH * (float)SEQ)));
}

extern "C" void kernel_launch(void* const* d_in, const int* in_sizes, int n_in,
                              void* d_out, int out_size, void* d_ws, size_t ws_size,
                              hipStream_t stream) {
    const float* logits = (const float*)d_in[0];
    const int*   target = (const int*)d_in[1];

    int* words = (int*)d_ws;   // BATCH*SEQ ints
    float* out = (float*)d_out;

    argmax_kernel<<<BATCH * SEQ / 4, 256, 0, stream>>>(logits, words, out);
    editdist_kernel<<<BATCH, 64, 0, stream>>>(words, target, out);
}